// Round 7
// baseline (300.808 us; speedup 1.0000x reference)
//
#include <hip/hip_runtime.h>
#include <hip/hip_cooperative_groups.h>

namespace cg = cooperative_groups;

#define F_ALL 20000
#define FP    10000
#define BB    4
#define KK    16
#define OO    128
#define NFACE 40000
#define NTILE 625            // 64 faces per tile

// workspace float offsets
#define WS_FEAT 0
#define WS_AGG  (BB*F_ALL*64)            // 5,120,000
#define WS_GP   (WS_AGG + NFACE*64)      // 7,680,000
#define WS_SAP  (WS_GP + NTILE*4096)     // 10,240,000
#define WS_MT   (WS_SAP + NTILE*64)      // 10,280,000  MT[j*64+i] = A[i][j]
#define WS_V0   (WS_MT + 4096)
#define WS_G    (WS_V0 + 64)
#define WS_SUMA (WS_G + 4096)

// LDS float offsets (13056 floats = 52.2 KB total, no extra __shared__)
#define L_R1   4352
#define L_GS   8448
#define L_QS   8512
#define L_SC   12800
#define L_SH   12928

template<int CTRL>
__device__ __forceinline__ float dpp_add(float x) {
    return x + __int_as_float(__builtin_amdgcn_update_dpp(0, __float_as_int(x), CTRL, 0xF, 0xF, true));
}
__device__ __forceinline__ float sum16(float x) {
    x = dpp_add<0x121>(x);
    x = dpp_add<0x122>(x);
    x = dpp_add<0x124>(x);
    x = dpp_add<0x128>(x);
    return x;
}

// phase: -1 = all phases with grid.sync (cooperative); 0..3 = single phase (fallback)
__global__ __launch_bounds__(256, 2) void k_fused(const float* __restrict__ fea,
                                                  const int* __restrict__ ring,
                                                  const int* __restrict__ pool,
                                                  const float* __restrict__ Wk,
                                                  const float* __restrict__ bk,
                                                  const float* __restrict__ Wq,
                                                  const float* __restrict__ Wc,
                                                  const float* __restrict__ bc,
                                                  const float* __restrict__ gamma,
                                                  const float* __restrict__ beta,
                                                  float* __restrict__ ws,
                                                  float* __restrict__ out,
                                                  int phase) {
    __shared__ __align__(16) float lds[13056];
    cg::grid_group grid = cg::this_grid();
    const int tid  = threadIdx.x;
    const int bid  = blockIdx.x;
    const int GRID = gridDim.x;
    const bool coop = (phase < 0);
    const float scale = 0.08838834764831845f;   // 1/sqrt(128)

    // ================= Phase A: transpose fea -> feaT, precompute A/v0 =================
    if (coop || phase == 0) {
        float* tile = lds;                      // [64][65]
        float* feaT = ws + WS_FEAT;
        for (int tb = bid; tb < 1252; tb += GRID) {
            __syncthreads();
            int bb = tb / 313;
            int fbase = (tb % 313) * 64;
            int x  = tid & 63;
            int y0 = tid >> 6;
            int f = fbase + x;
            if (f < F_ALL) {
#pragma unroll
                for (int i = 0; i < 16; i++) {
                    int c = y0 + i * 4;
                    tile[c * 65 + x] = fea[((long)bb * 64 + c) * F_ALL + f];
                }
            }
            __syncthreads();
#pragma unroll
            for (int i = 0; i < 16; i++) {
                int fr = y0 + i * 4;
                int ff = fbase + fr;
                if (ff < F_ALL)
                    feaT[((long)bb * F_ALL + ff) * 64 + x] = tile[x * 65 + fr];
            }
        }
        if (bid < 16) {
            int idx = bid * 256 + tid;          // 0..4095
            int j = idx >> 6, i = idx & 63;
            float acc = 0.f;
#pragma unroll 8
            for (int o = 0; o < 128; o++) acc += Wq[o * 64 + i] * Wk[o * 64 + j];
            ws[WS_MT + idx] = acc;              // MT[j*64+i] = A[i][j]
        } else if (bid == 16 && tid < 64) {
            float a = 0.f;
            for (int o = 0; o < 128; o++) a += Wq[o * 64 + tid] * bk[o];
            ws[WS_V0 + tid] = a;
            ws[WS_SUMA + tid] = 0.f;            // zeroed for C1 atomics
        }
    }
    if (coop) grid.sync();

    // ================= Phase B: qvec + attention + gram partial (64 faces/tile) =================
    if (coop || phase == 1) {
        float* Sf = lds;                 // stride 65, [0,4160)
        float* U  = lds + L_R1;          // stride 68, [4352,8704)
        float* At = lds + 8704;          // [4096]
        const float* feaT = ws + WS_FEAT;
        int ti = tid & 15, tj = tid >> 4;
        int lane = tid & 63;
        int il = lane & 15, c4 = il * 4;

        for (int i = tid; i < 4096; i += 256) At[i] = ws[WS_MT + i];   // persists across tiles

        for (int tile = bid; tile < NTILE; tile += GRID) {
            int fbase = tile * 64;
            __syncthreads();             // protects prev-iter Ag reads + At load

            // B1: gather self rows
            {
                int r = tid >> 2;
                int face = fbase + r;
                int b = face / FP;
                int p = pool[face - b * FP];
                const float* src = feaT + ((long)(b * F_ALL + p)) * 64;
                int off = (tid & 3) * 4;
#pragma unroll
                for (int it = 0; it < 4; it++, off += 16) {
                    float4 v = *(const float4*)(src + off);
                    Sf[r * 65 + off + 0] = v.x;
                    Sf[r * 65 + off + 1] = v.y;
                    Sf[r * 65 + off + 2] = v.z;
                    Sf[r * 65 + off + 3] = v.w;
                }
            }
            __syncthreads();

            // B2: U = Sf * A + v0
            {
                int f0 = ti * 4, o0 = tj * 4;
                float4 v0 = *(const float4*)&ws[WS_V0 + o0];
                float acc[4][4];
#pragma unroll
                for (int a = 0; a < 4; a++) {
                    acc[a][0] = v0.x; acc[a][1] = v0.y; acc[a][2] = v0.z; acc[a][3] = v0.w;
                }
                for (int j = 0; j < 64; j++) {
                    float4 wv = *(const float4*)&At[j * 64 + o0];
#pragma unroll
                    for (int a = 0; a < 4; a++) {
                        float av = Sf[(f0 + a) * 65 + j];
                        acc[a][0] += av * wv.x;
                        acc[a][1] += av * wv.y;
                        acc[a][2] += av * wv.z;
                        acc[a][3] += av * wv.w;
                    }
                }
#pragma unroll
                for (int a = 0; a < 4; a++)
                    *(float4*)&U[(f0 + a) * 68 + o0] =
                        make_float4(acc[a][0], acc[a][1], acc[a][2], acc[a][3]);
            }
            __syncthreads();

            // B3: attention (wave = 4 faces, 4 iterations), results in regs
            float4 a_res[4];
            for (int it = 0; it < 4; it++) {
                int fl = (tid >> 4) + it * 16;
                int face = fbase + fl;
                int b = face / FP;
                const float* fb = feaT + ((long)b * F_ALL) * 64 + c4;

                float4 sf = make_float4(Sf[fl * 65 + c4], Sf[fl * 65 + c4 + 1],
                                        Sf[fl * 65 + c4 + 2], Sf[fl * 65 + c4 + 3]);
                float4 u = *(const float4*)&U[fl * 68 + c4];

                int rv = ring[face * KK + il];
                float4 nv[KK];
#pragma unroll
                for (int k = 0; k < KK; k++) {
                    int rk = __shfl(rv, (lane & 48) | k, 64);
                    nv[k] = *(const float4*)(fb + (long)rk * 64);
                }

                float l[KK + 1];
                l[0] = sum16(u.x * sf.x + u.y * sf.y + u.z * sf.z + u.w * sf.w) * scale;
#pragma unroll
                for (int k = 0; k < KK; k++)
                    l[k + 1] = sum16(u.x * nv[k].x + u.y * nv[k].y + u.z * nv[k].z + u.w * nv[k].w) * scale;

                float m = l[0];
#pragma unroll
                for (int k = 1; k <= KK; k++) m = fmaxf(m, l[k]);
                float den = 0.f;
#pragma unroll
                for (int k = 0; k <= KK; k++) { l[k] = __expf(l[k] - m); den += l[k]; }
                float inv = 1.0f / den;

                float4 a;
                a.x = l[0] * sf.x; a.y = l[0] * sf.y; a.z = l[0] * sf.z; a.w = l[0] * sf.w;
#pragma unroll
                for (int k = 0; k < KK; k++) {
                    a.x += l[k + 1] * nv[k].x;
                    a.y += l[k + 1] * nv[k].y;
                    a.z += l[k + 1] * nv[k].z;
                    a.w += l[k + 1] * nv[k].w;
                }
                a.x *= inv; a.y *= inv; a.z *= inv; a.w *= inv;
                a_res[it] = a;
                *(float4*)&ws[WS_AGG + (long)face * 64 + c4] = a;
            }
            __syncthreads();            // Sf reads done -> safe to overwrite with Ag
            float* Ag = lds;
#pragma unroll
            for (int it = 0; it < 4; it++) {
                int fl = (tid >> 4) + it * 16;
                *(float4*)&Ag[fl * 64 + c4] = a_res[it];
            }
            __syncthreads();

            // B4: per-tile gram partial
            float acc[4][4];
#pragma unroll
            for (int a = 0; a < 4; a++)
#pragma unroll
                for (int b = 0; b < 4; b++) acc[a][b] = 0.f;
            float gacc[4] = {0.f, 0.f, 0.f, 0.f};
#pragma unroll 4
            for (int f = 0; f < 64; f++) {
                float4 av = *(const float4*)&Ag[f * 64 + ti * 4];
                float4 bv = *(const float4*)&Ag[f * 64 + tj * 4];
                float avv[4] = {av.x, av.y, av.z, av.w};
                float bvv[4] = {bv.x, bv.y, bv.z, bv.w};
#pragma unroll
                for (int a = 0; a < 4; a++) {
#pragma unroll
                    for (int b = 0; b < 4; b++) acc[a][b] += avv[a] * bvv[b];
                    gacc[a] += avv[a];
                }
            }
            float* gp = ws + WS_GP;
#pragma unroll
            for (int a = 0; a < 4; a++)
                *(float4*)&gp[(long)tile * 4096 + (ti * 4 + a) * 64 + tj * 4] =
                    make_float4(acc[a][0], acc[a][1], acc[a][2], acc[a][3]);
            if (tj == 0)
                *(float4*)&ws[WS_SAP + tile * 64 + ti * 4] =
                    make_float4(gacc[0], gacc[1], gacc[2], gacc[3]);
        }
    }
    if (coop) grid.sync();

    // ================= Phase C1: reduce gram partials (slots 0..259, grid-stride) =================
    if (coop || phase == 2) {
        float* red = lds;               // [256]
        for (int v = bid; v < 260; v += GRID) {
            __syncthreads();
            if (v < 256) {
                const float* gp = ws + WS_GP;
                int e16 = v * 16;
                int e = tid & 15, c = tid >> 4;
                int p0 = c * 40;
                int p1 = p0 + 40; if (p1 > NTILE) p1 = NTILE;
                float s0 = 0.f, s1 = 0.f, s2 = 0.f, s3 = 0.f;
                int p = p0;
                for (; p + 4 <= p1; p += 4) {
                    s0 += gp[(long)(p + 0) * 4096 + e16 + e];
                    s1 += gp[(long)(p + 1) * 4096 + e16 + e];
                    s2 += gp[(long)(p + 2) * 4096 + e16 + e];
                    s3 += gp[(long)(p + 3) * 4096 + e16 + e];
                }
                for (; p < p1; p++) s0 += gp[(long)p * 4096 + e16 + e];
                red[tid] = (s0 + s1) + (s2 + s3);
                __syncthreads();
                if (tid < 16) {
                    float s = 0.f;
#pragma unroll
                    for (int cc = 0; cc < 16; cc++) s += red[cc * 16 + tid];
                    ws[WS_G + e16 + tid] = s;
                }
            } else {
                const float* sap = ws + WS_SAP;
                int bq = v - 256;
                int e = tid & 63, c = tid >> 6;
                int pidx = bq * 4 + c;
                int p0 = pidx * 40;
                int p1 = p0 + 40; if (p1 > NTILE) p1 = NTILE;
                float s0 = 0.f, s1 = 0.f, s2 = 0.f, s3 = 0.f;
                int p = p0;
                for (; p + 4 <= p1; p += 4) {
                    s0 += sap[(p + 0) * 64 + e];
                    s1 += sap[(p + 1) * 64 + e];
                    s2 += sap[(p + 2) * 64 + e];
                    s3 += sap[(p + 3) * 64 + e];
                }
                for (; p < p1; p++) s0 += sap[p * 64 + e];
                red[tid] = (s0 + s1) + (s2 + s3);
                __syncthreads();
                if (tid < 64) {
                    float tot = red[tid] + red[tid + 64] + red[tid + 128] + red[tid + 192];
                    atomicAdd(&ws[WS_SUMA + tid], tot);
                }
            }
        }
    }
    if (coop) grid.sync();

    // ================= Phase C2 + D =================
    if (coop || phase == 3) {
        // C2: BN stats, redundant per block (G is 16KB, L2-hot)
        {
            float* Gs = lds + L_R1;
            float* gs = lds + L_GS;
            float* qs = lds + L_QS;
            __syncthreads();
            for (int i = tid; i < 4096; i += 256) Gs[i] = ws[WS_G + i];
            if (tid < 64) gs[tid] = ws[WS_SUMA + tid];
            __syncthreads();

            int o = tid & 127, h = tid >> 7;
            float w[64];
#pragma unroll
            for (int q = 0; q < 16; q++) {
                float4 t = *(const float4*)&Wc[o * 64 + q * 4];
                w[q * 4 + 0] = t.x; w[q * 4 + 1] = t.y; w[q * 4 + 2] = t.z; w[q * 4 + 3] = t.w;
            }
            float qp = 0.f;
            for (int i = h * 32; i < h * 32 + 32; i++) {
                float t = 0.f;
#pragma unroll
                for (int j = 0; j < 64; j++) t += Gs[i * 64 + j] * w[j];
                qp += Wc[o * 64 + i] * t;
            }
            qs[tid] = qp;
            __syncthreads();
            if (h == 0) {
                const float invN = 1.0f / (float)NFACE;
                float qform = qs[o] + qs[o + 128];
                float md = 0.f;
#pragma unroll
                for (int j = 0; j < 64; j++) md += gs[j] * w[j];
                float bco = bc[o];
                float mean = md * invN + bco;
                float ey2  = (qform + 2.f * bco * md) * invN + bco * bco;
                float var  = ey2 - mean * mean;
                float sc   = gamma[o] * rsqrtf(var + 1e-5f);
                lds[L_SC + o] = sc;
                lds[L_SH + o] = beta[o] + (bco - mean) * sc;
            }
            __syncthreads();
        }
        // D: out = relu((Wc*agg)*sc + sh)
        {
            float* AgT = lds;                // [j*68+f]  [0,4352)
            float* WcT = lds + L_R1;         // [j*132+o] [4352,12800)
            const float* agg = ws + WS_AGG;
            for (int i = tid; i < 128 * 64; i += 256) {
                int o = i >> 6, j = i & 63;
                WcT[j * 132 + o] = Wc[i];            // persists across tiles
            }
            int tx = tid & 15, ty = tid >> 4;
            for (int tile = bid; tile < NTILE; tile += GRID) {
                int fbase = tile * 64;
                __syncthreads();         // protects prev AgT reads + first WcT visibility ordering
                for (int i = tid; i < 64 * 64; i += 256) {
                    int f = i >> 6, j = i & 63;
                    AgT[j * 68 + f] = agg[((long)(fbase + f)) * 64 + j];
                }
                __syncthreads();

                float acc[8][4];
#pragma unroll
                for (int a = 0; a < 8; a++)
#pragma unroll
                    for (int b = 0; b < 4; b++) acc[a][b] = 0.f;

                for (int j = 0; j < 64; j++) {
                    float4 w0 = *(const float4*)&WcT[j * 132 + ty * 8];
                    float4 w1 = *(const float4*)&WcT[j * 132 + ty * 8 + 4];
                    float4 a0 = *(const float4*)&AgT[j * 68 + tx * 4];
                    float wv[8] = {w0.x, w0.y, w0.z, w0.w, w1.x, w1.y, w1.z, w1.w};
                    float av[4] = {a0.x, a0.y, a0.z, a0.w};
#pragma unroll
                    for (int oi = 0; oi < 8; oi++)
#pragma unroll
                        for (int fi = 0; fi < 4; fi++) acc[oi][fi] += wv[oi] * av[fi];
                }

                int fg0 = fbase + tx * 4;
                int b   = fg0 / FP;
                int fp0 = fg0 - b * FP;      // 4-runs never cross batch (10000 % 4 == 0)
#pragma unroll
                for (int oi = 0; oi < 8; oi++) {
                    int o = ty * 8 + oi;
                    float sc = lds[L_SC + o];
                    float sh = lds[L_SH + o];
                    float4 v;
                    v.x = fmaxf(acc[oi][0] * sc + sh, 0.f);
                    v.y = fmaxf(acc[oi][1] * sc + sh, 0.f);
                    v.z = fmaxf(acc[oi][2] * sc + sh, 0.f);
                    v.w = fmaxf(acc[oi][3] * sc + sh, 0.f);
                    *(float4*)&out[((long)(b * OO + o)) * FP + fp0] = v;
                }
            }
        }
    }
}

extern "C" void kernel_launch(void* const* d_in, const int* in_sizes, int n_in,
                              void* d_out, int out_size, void* d_ws, size_t ws_size,
                              hipStream_t stream) {
    const float* fea  = (const float*)d_in[0];
    const int*   ring = (const int*)d_in[1];
    const int*   pool = (const int*)d_in[2];
    const float* Wk = (const float*)d_in[4];
    const float* bk = (const float*)d_in[5];
    const float* Wq = (const float*)d_in[6];
    // bq unused: its logit contribution is constant per face -> cancels in softmax
    const float* Wc = (const float*)d_in[8];
    const float* bc = (const float*)d_in[9];
    const float* gamma = (const float*)d_in[10];
    const float* beta  = (const float*)d_in[11];

    float* out = (float*)d_out;
    float* ws  = (float*)d_ws;

    // capacity-aware cooperative grid (pure query, deterministic, capture-safe)
    int maxb = 0;
    hipError_t qe = hipOccupancyMaxActiveBlocksPerMultiprocessor(&maxb, (const void*)k_fused, 256, 0);
    int grid = (qe == hipSuccess && maxb > 0) ? maxb * 256 : 0;   // 256 CUs on MI355X
    if (grid > NTILE) grid = NTILE;

    hipError_t le = hipErrorUnknown;
    if (grid >= 64) {
        int phase = -1;
        void* kargs[] = {(void*)&fea, (void*)&ring, (void*)&pool, (void*)&Wk, (void*)&bk,
                         (void*)&Wq, (void*)&Wc, (void*)&bc, (void*)&gamma, (void*)&beta,
                         (void*)&ws, (void*)&out, (void*)&phase};
        le = hipLaunchCooperativeKernel((const void*)k_fused, dim3(grid), dim3(256), kargs, 0, stream);
    }
    if (le != hipSuccess) {
        // fallback: phases as separate launches (grid.sync replaced by kernel boundaries)
        for (int ph = 0; ph < 4; ph++)
            k_fused<<<512, 256, 0, stream>>>(fea, ring, pool, Wk, bk, Wq, Wc, bc,
                                             gamma, beta, ws, out, ph);
    }
}

// Round 8
// 181.612 us; speedup vs baseline: 1.6563x; 1.6563x over previous
//
#include <hip/hip_runtime.h>

#define F_ALL 20000
#define FP    10000
#define BB    4
#define KK    16
#define OO    128
#define NFACE 40000
#define NGRAMB 125           // gram partial blocks (125*320 = 40000 faces)

// workspace float offsets
#define WS_FEAT 0
#define WS_AGG  (BB*F_ALL*64)            // 5,120,000
#define WS_GP   (WS_AGG + NFACE*64)      // 7,680,000
#define WS_SAP  (WS_GP + NGRAMB*4096)    // 8,192,000
#define WS_MT   (WS_SAP + NGRAMB*64)     // 8,200,000   MT[j*64+i] = A[i][j]
#define WS_V0   (WS_MT + 4096)
#define WS_G    (WS_V0 + 64)
#define WS_SUMA (WS_G + 4096)
#define WS_SC   (WS_SUMA + 64)
#define WS_SH   (WS_SC + 128)

template<int CTRL>
__device__ __forceinline__ float dpp_add(float x) {
    return x + __int_as_float(__builtin_amdgcn_update_dpp(0, __float_as_int(x), CTRL, 0xF, 0xF, true));
}
// all-reduce sum within each 16-lane row (4 VALU DPP stages)
__device__ __forceinline__ float sum16(float x) {
    x = dpp_add<0x121>(x);
    x = dpp_add<0x122>(x);
    x = dpp_add<0x124>(x);
    x = dpp_add<0x128>(x);
    return x;
}

// ---------- K1: transpose fea -> feaT (blocks 0..1251) + precompute (1252..1267) ----------
__global__ __launch_bounds__(256) void k_pre(const float* __restrict__ fea,
                                             const float* __restrict__ Wk,
                                             const float* __restrict__ bk,
                                             const float* __restrict__ Wq,
                                             float* __restrict__ ws) {
    __shared__ float tile[64][65];
    int tid = threadIdx.x;
    if (blockIdx.x < 1252) {
        int bb = blockIdx.x / 313;
        int tb = blockIdx.x % 313;
        int fbase = tb * 64;
        int x  = tid & 63;
        int y0 = tid >> 6;
        int f = fbase + x;
        float* feaT = ws + WS_FEAT;
        if (f < F_ALL) {
#pragma unroll
            for (int i = 0; i < 16; i++) {
                int c = y0 + i * 4;
                tile[c][x] = fea[((long)bb * 64 + c) * F_ALL + f];
            }
        }
        __syncthreads();
#pragma unroll
        for (int i = 0; i < 16; i++) {
            int fr = y0 + i * 4;
            int ff = fbase + fr;
            if (ff < F_ALL)
                feaT[((long)bb * F_ALL + ff) * 64 + x] = tile[x][fr];
        }
    } else {
        int idx = (blockIdx.x - 1252) * 256 + tid;    // 0..4095
        int j = idx >> 6, i = idx & 63;
        float acc = 0.f;
#pragma unroll 8
        for (int o = 0; o < 128; o++) acc += Wq[o * 64 + i] * Wk[o * 64 + j];
        ws[WS_MT + idx] = acc;                        // MT[j*64+i] = A[i][j]
        if (blockIdx.x == 1252 && tid < 64) {
            float a = 0.f;
            for (int o = 0; o < 128; o++) a += Wq[o * 64 + tid] * bk[o];
            ws[WS_V0 + tid] = a;
            ws[WS_SUMA + tid] = 0.f;                  // zero for k_gsum atomics
        }
    }
}

// ---------- K2: attention, 32 faces/block, 1250 blocks, u in registers ----------
__global__ __launch_bounds__(256) void k_attn(const int* __restrict__ ring,
                                              const int* __restrict__ pool,
                                              float* __restrict__ ws) {
    __shared__ __align__(16) float MTl[4096];   // A^T staged (16 KB)
    __shared__ float Sf[32 * 65];               // self rows (8.3 KB)
    int tid = threadIdx.x;
    int fbase = blockIdx.x * 32;
    const float* feaT = ws + WS_FEAT;
    const float scale = 0.08838834764831845f;   // 1/sqrt(128)

    for (int i = tid; i < 4096; i += 256) MTl[i] = ws[WS_MT + i];
    {
        int r = tid >> 3;                 // 0..31
        int face = fbase + r;
        int b = face / FP;
        int p = pool[face - b * FP];
        const float* src = feaT + ((long)(b * F_ALL + p)) * 64 + (tid & 7) * 8;
        float4 v0 = *(const float4*)src;
        float4 v1 = *(const float4*)(src + 4);
        float* dst = &Sf[r * 65 + (tid & 7) * 8];
        dst[0] = v0.x; dst[1] = v0.y; dst[2] = v0.z; dst[3] = v0.w;
        dst[4] = v1.x; dst[5] = v1.y; dst[6] = v1.z; dst[7] = v1.w;
    }
    __syncthreads();

    int lane = tid & 63;
    int il = lane & 15, c4 = il * 4;
    float4 uv0 = *(const float4*)&ws[WS_V0 + c4];

    for (int it = 0; it < 2; it++) {
        int fl = (tid >> 4) + it * 16;
        int face = fbase + fl;
        int b = face / FP;
        const float* fb = feaT + ((long)b * F_ALL) * 64 + c4;

        float4 sf = make_float4(Sf[fl * 65 + c4], Sf[fl * 65 + c4 + 1],
                                Sf[fl * 65 + c4 + 2], Sf[fl * 65 + c4 + 3]);

        // neighbor gathers issued early
        int rv = ring[face * KK + il];
        float4 nv[KK];
#pragma unroll
        for (int k = 0; k < KK; k++) {
            int rk = __shfl(rv, (lane & 48) | k, 64);
            nv[k] = *(const float4*)(fb + (long)rk * 64);
        }

        // u[c4..c4+3] = v0 + sum_j A[c4..][j] * sf[j]  (MT/Sf from LDS)
        float4 u = uv0;
#pragma unroll 8
        for (int j = 0; j < 64; j++) {
            float aj = Sf[fl * 65 + j];
            float4 m4 = *(const float4*)&MTl[j * 64 + c4];
            u.x += m4.x * aj;
            u.y += m4.y * aj;
            u.z += m4.z * aj;
            u.w += m4.w * aj;
        }

        float l[KK + 1];
        l[0] = sum16(u.x * sf.x + u.y * sf.y + u.z * sf.z + u.w * sf.w) * scale;
#pragma unroll
        for (int k = 0; k < KK; k++)
            l[k + 1] = sum16(u.x * nv[k].x + u.y * nv[k].y + u.z * nv[k].z + u.w * nv[k].w) * scale;

        float m = l[0];
#pragma unroll
        for (int k = 1; k <= KK; k++) m = fmaxf(m, l[k]);
        float den = 0.f;
#pragma unroll
        for (int k = 0; k <= KK; k++) { l[k] = __expf(l[k] - m); den += l[k]; }
        float inv = 1.0f / den;

        float4 a;
        a.x = l[0] * sf.x; a.y = l[0] * sf.y; a.z = l[0] * sf.z; a.w = l[0] * sf.w;
#pragma unroll
        for (int k = 0; k < KK; k++) {
            a.x += l[k + 1] * nv[k].x;
            a.y += l[k + 1] * nv[k].y;
            a.z += l[k + 1] * nv[k].z;
            a.w += l[k + 1] * nv[k].w;
        }
        a.x *= inv; a.y *= inv; a.z *= inv; a.w *= inv;
        *(float4*)&ws[WS_AGG + (long)face * 64 + c4] = a;
    }
}

// ---------- K3: Gram partials (privatized, no atomics; agg is L2/L3-hot) ----------
__global__ __launch_bounds__(256) void k_gram(float* __restrict__ ws) {
    __shared__ float lbuf[4096];
    const float* agg = ws + WS_AGG;
    int tid = threadIdx.x;
    int ti = tid & 15, tj = tid >> 4;
    float acc[4][4];
#pragma unroll
    for (int a = 0; a < 4; a++)
#pragma unroll
        for (int b = 0; b < 4; b++) acc[a][b] = 0.f;
    float gacc[4] = {0.f, 0.f, 0.f, 0.f};

    for (int c = 0; c < 5; c++) {
        int fbase = blockIdx.x * 320 + c * 64;
        const float4* src = (const float4*)(agg + (long)fbase * 64);
        float4* dst = (float4*)lbuf;
        __syncthreads();
        for (int i = tid; i < 1024; i += 256) dst[i] = src[i];
        __syncthreads();
#pragma unroll 4
        for (int f = 0; f < 64; f++) {
            float4 av = *(const float4*)&lbuf[f * 64 + ti * 4];
            float4 bv = *(const float4*)&lbuf[f * 64 + tj * 4];
            float avv[4] = {av.x, av.y, av.z, av.w};
            float bvv[4] = {bv.x, bv.y, bv.z, bv.w};
#pragma unroll
            for (int a = 0; a < 4; a++) {
#pragma unroll
                for (int b = 0; b < 4; b++) acc[a][b] += avv[a] * bvv[b];
                gacc[a] += avv[a];
            }
        }
    }
    float* gp = ws + WS_GP;
#pragma unroll
    for (int a = 0; a < 4; a++)
        *(float4*)&gp[(long)blockIdx.x * 4096 + (ti * 4 + a) * 64 + tj * 4] =
            make_float4(acc[a][0], acc[a][1], acc[a][2], acc[a][3]);
    if (tj == 0)
        *(float4*)&ws[WS_SAP + blockIdx.x * 64 + ti * 4] =
            make_float4(gacc[0], gacc[1], gacc[2], gacc[3]);
}

// ---------- K4: reduce gram partials (256 blocks for G, 4 for sumA) ----------
__global__ __launch_bounds__(256) void k_gsum(float* __restrict__ ws) {
    __shared__ float red[256];
    int t = threadIdx.x;
    if (blockIdx.x < 256) {
        const float* gp = ws + WS_GP;
        int e16 = blockIdx.x * 16;
        int e = t & 15, c = t >> 4;          // 16 p-chunks of 8
        int p0 = c * 8;
        int p1 = p0 + 8; if (p1 > NGRAMB) p1 = NGRAMB;
        float s0 = 0.f, s1 = 0.f, s2 = 0.f, s3 = 0.f;
        int p = p0;
        for (; p + 4 <= p1; p += 4) {
            s0 += gp[(long)(p + 0) * 4096 + e16 + e];
            s1 += gp[(long)(p + 1) * 4096 + e16 + e];
            s2 += gp[(long)(p + 2) * 4096 + e16 + e];
            s3 += gp[(long)(p + 3) * 4096 + e16 + e];
        }
        for (; p < p1; p++) s0 += gp[(long)p * 4096 + e16 + e];
        red[t] = (s0 + s1) + (s2 + s3);
        __syncthreads();
        if (t < 16) {
            float s = 0.f;
#pragma unroll
            for (int cc = 0; cc < 16; cc++) s += red[cc * 16 + t];
            ws[WS_G + e16 + t] = s;
        }
    } else {
        const float* sap = ws + WS_SAP;
        int bq = blockIdx.x - 256;           // 0..3
        int e = t & 63, c = t >> 6;
        int pidx = bq * 4 + c;               // 0..15, chunks of 8
        int p0 = pidx * 8;
        int p1 = p0 + 8; if (p1 > NGRAMB) p1 = NGRAMB;
        float s0 = 0.f, s1 = 0.f, s2 = 0.f, s3 = 0.f;
        int p = p0;
        for (; p + 4 <= p1; p += 4) {
            s0 += sap[(p + 0) * 64 + e];
            s1 += sap[(p + 1) * 64 + e];
            s2 += sap[(p + 2) * 64 + e];
            s3 += sap[(p + 3) * 64 + e];
        }
        for (; p < p1; p++) s0 += sap[p * 64 + e];
        red[t] = (s0 + s1) + (s2 + s3);
        __syncthreads();
        if (t < 64) {
            float tot = red[t] + red[t + 64] + red[t + 128] + red[t + 192];
            atomicAdd(&ws[WS_SUMA + t], tot);   // 4 blocks x 64 atomics
        }
    }
}

// ---------- K5: BN stats -> per-o scale/shift ----------
__global__ __launch_bounds__(256) void k_stats(const float* __restrict__ Wc,
                                               const float* __restrict__ bc,
                                               const float* __restrict__ gamma,
                                               const float* __restrict__ beta,
                                               float* __restrict__ ws) {
    __shared__ float Gs[4096];
    __shared__ float gs[64];
    __shared__ float qs[256];
    int tid = threadIdx.x;
    for (int i = tid; i < 4096; i += 256) Gs[i] = ws[WS_G + i];
    if (tid < 64) gs[tid] = ws[WS_SUMA + tid];
    __syncthreads();

    int o = tid & 127, h = tid >> 7;
    float w[64];
#pragma unroll
    for (int q = 0; q < 16; q++) {
        float4 t = *(const float4*)&Wc[o * 64 + q * 4];
        w[q * 4 + 0] = t.x; w[q * 4 + 1] = t.y; w[q * 4 + 2] = t.z; w[q * 4 + 3] = t.w;
    }
    float qp = 0.f;
    for (int i = h * 32; i < h * 32 + 32; i++) {
        float t = 0.f;
#pragma unroll
        for (int j = 0; j < 64; j++) t += Gs[i * 64 + j] * w[j];
        qp += Wc[o * 64 + i] * t;
    }
    qs[tid] = qp;
    __syncthreads();
    if (h == 0) {
        const float invN = 1.0f / (float)NFACE;
        float qform = qs[o] + qs[o + 128];
        float md = 0.f;
#pragma unroll
        for (int j = 0; j < 64; j++) md += gs[j] * w[j];
        float bco = bc[o];
        float mean = md * invN + bco;
        float ey2  = (qform + 2.f * bco * md) * invN + bco * bco;
        float var  = ey2 - mean * mean;
        float sc   = gamma[o] * rsqrtf(var + 1e-5f);
        ws[WS_SC + o] = sc;
        ws[WS_SH + o] = beta[o] + (bco - mean) * sc;
    }
}

// ---------- K6: out = relu((Wc*agg)*sc + sh)  [B,O,Fp] ----------
__global__ __launch_bounds__(256) void k_out(const float* __restrict__ Wc,
                                             const float* __restrict__ ws,
                                             float* __restrict__ out) {
    __shared__ __align__(16) float WcT[64 * 132];   // [j][o]
    __shared__ __align__(16) float AgT[64 * 68];    // [j][f]
    const float* agg = ws + WS_AGG;
    int tid = threadIdx.x;
    int fbase = blockIdx.x * 64;
    for (int i = tid; i < 128 * 64; i += 256) {
        int o = i >> 6, j = i & 63;
        WcT[j * 132 + o] = Wc[i];
    }
    for (int i = tid; i < 64 * 64; i += 256) {
        int f = i >> 6, j = i & 63;
        AgT[j * 68 + f] = agg[((long)(fbase + f)) * 64 + j];
    }
    __syncthreads();

    int tx = tid & 15, ty = tid >> 4;   // tx: 4 faces, ty: 8 outputs
    float acc[8][4];
#pragma unroll
    for (int a = 0; a < 8; a++)
#pragma unroll
        for (int b = 0; b < 4; b++) acc[a][b] = 0.f;

    for (int j = 0; j < 64; j++) {
        float4 w0 = *(const float4*)&WcT[j * 132 + ty * 8];
        float4 w1 = *(const float4*)&WcT[j * 132 + ty * 8 + 4];
        float4 a0 = *(const float4*)&AgT[j * 68 + tx * 4];
        float wv[8] = {w0.x, w0.y, w0.z, w0.w, w1.x, w1.y, w1.z, w1.w};
        float av[4] = {a0.x, a0.y, a0.z, a0.w};
#pragma unroll
        for (int oi = 0; oi < 8; oi++)
#pragma unroll
            for (int fi = 0; fi < 4; fi++) acc[oi][fi] += wv[oi] * av[fi];
    }

    int fg0 = fbase + tx * 4;
    int b   = fg0 / FP;
    int fp0 = fg0 - b * FP;             // 4-runs never cross batch boundary
#pragma unroll
    for (int oi = 0; oi < 8; oi++) {
        int o = ty * 8 + oi;
        float sc = ws[WS_SC + o];
        float sh = ws[WS_SH + o];
        float4 v;
        v.x = fmaxf(acc[oi][0] * sc + sh, 0.f);
        v.y = fmaxf(acc[oi][1] * sc + sh, 0.f);
        v.z = fmaxf(acc[oi][2] * sc + sh, 0.f);
        v.w = fmaxf(acc[oi][3] * sc + sh, 0.f);
        *(float4*)&out[((long)(b * OO + o)) * FP + fp0] = v;
    }
}

extern "C" void kernel_launch(void* const* d_in, const int* in_sizes, int n_in,
                              void* d_out, int out_size, void* d_ws, size_t ws_size,
                              hipStream_t stream) {
    const float* fea  = (const float*)d_in[0];
    const int*   ring = (const int*)d_in[1];
    const int*   pool = (const int*)d_in[2];
    const float* Wk = (const float*)d_in[4];
    const float* bk = (const float*)d_in[5];
    const float* Wq = (const float*)d_in[6];
    // bq unused: its logit contribution is constant per face -> cancels in softmax
    const float* Wc = (const float*)d_in[8];
    const float* bc = (const float*)d_in[9];
    const float* gamma = (const float*)d_in[10];
    const float* beta  = (const float*)d_in[11];

    float* out = (float*)d_out;
    float* ws  = (float*)d_ws;

    k_pre  <<<1268, 256, 0, stream>>>(fea, Wk, bk, Wq, ws);
    k_attn <<<1250, 256, 0, stream>>>(ring, pool, ws);
    k_gram <<<NGRAMB, 256, 0, stream>>>(ws);
    k_gsum <<<260,  256, 0, stream>>>(ws);
    k_stats<<<1,    256, 0, stream>>>(Wc, bc, gamma, beta, ws);
    k_out  <<<625,  256, 0, stream>>>(Wc, ws, out);
}

// Round 10
// 168.084 us; speedup vs baseline: 1.7896x; 1.0805x over previous
//
#include <hip/hip_runtime.h>

#define F_ALL 20000
#define FP    10000
#define BB    4
#define KK    16
#define OO    128
#define NFACE 40000
#define NBLK  625            // 64 faces per attn block

// workspace float offsets (~41 MB total)
#define WS_FEAT 0
#define WS_AGG  (BB*F_ALL*64)            // 5,120,000
#define WS_GP   (WS_AGG + NFACE*64)      // 7,680,000
#define WS_SAP  (WS_GP + NBLK*4096)      // 10,240,000
#define WS_MT   (WS_SAP + NBLK*64)       // 10,280,000  MT[j*64+i] = A[i][j]
#define WS_V0   (WS_MT + 4096)
#define WS_G    (WS_V0 + 64)
#define WS_SUMA (WS_G + 4096)
#define WS_SC   (WS_SUMA + 64)
#define WS_SH   (WS_SC + 128)

template<int CTRL>
__device__ __forceinline__ float dpp_add(float x) {
    return x + __int_as_float(__builtin_amdgcn_update_dpp(0, __float_as_int(x), CTRL, 0xF, 0xF, true));
}
// all-reduce sum within each 16-lane row (4 VALU DPP stages)
__device__ __forceinline__ float sum16(float x) {
    x = dpp_add<0x121>(x);
    x = dpp_add<0x122>(x);
    x = dpp_add<0x124>(x);
    x = dpp_add<0x128>(x);
    return x;
}

// XCD-locality swizzle: default dispatch round-robins blockIdx across the 8
// XCDs (per-XCD private 4MB L2). Map launch index -> tile so each XCD owns a
// CONTIGUOUS ~79-tile face range (~= half of one batch, 5.12MB fp32 slice):
// neighbor gathers (random within batch) then hit that XCD's own L2.
// Bijection for 625 = 79 + 7*78: q=0 gets 79 tiles, q=1..7 get 78.
__device__ __forceinline__ int swz_tile(int bid) {
    int q = bid & 7, s = bid >> 3;
    return (q == 0) ? s : (79 + (q - 1) * 78 + s);
}

// ---------- K1: transpose fea -> feaT (blocks 0..1251) + precompute (1252..1267) ----------
__global__ __launch_bounds__(256) void k_pre(const float* __restrict__ fea,
                                             const float* __restrict__ Wk,
                                             const float* __restrict__ bk,
                                             const float* __restrict__ Wq,
                                             float* __restrict__ ws) {
    __shared__ float tile[64][65];
    int tid = threadIdx.x;
    if (blockIdx.x < 1252) {
        int bb = blockIdx.x / 313;
        int tb = blockIdx.x % 313;
        int fbase = tb * 64;
        int x  = tid & 63;
        int y0 = tid >> 6;
        int f = fbase + x;
        float* feaT = ws + WS_FEAT;
        if (f < F_ALL) {
#pragma unroll
            for (int i = 0; i < 16; i++) {
                int c = y0 + i * 4;
                tile[c][x] = fea[((long)bb * 64 + c) * F_ALL + f];
            }
        }
        __syncthreads();
#pragma unroll
        for (int i = 0; i < 16; i++) {
            int fr = y0 + i * 4;
            int ff = fbase + fr;
            if (ff < F_ALL)
                feaT[((long)bb * F_ALL + ff) * 64 + x] = tile[x][fr];
        }
    } else {
        int idx = (blockIdx.x - 1252) * 256 + tid;    // 0..4095
        int j = idx >> 6, i = idx & 63;
        float acc = 0.f;
#pragma unroll 8
        for (int o = 0; o < 128; o++) acc += Wq[o * 64 + i] * Wk[o * 64 + j];
        ws[WS_MT + idx] = acc;                        // MT[j*64+i] = A[i][j]
        if (blockIdx.x == 1252 && tid < 64) {
            float a = 0.f;
            for (int o = 0; o < 128; o++) a += Wq[o * 64 + tid] * bk[o];
            ws[WS_V0 + tid] = a;
            ws[WS_SUMA + tid] = 0.f;                  // zero for k_gsum atomics
        }
    }
}

// ---------- K2: fused qvec + attention + gram partial (64 faces / block) ----------
__global__ __launch_bounds__(256) void k_attn(const int* __restrict__ ring,
                                              const int* __restrict__ pool,
                                              float* __restrict__ ws) {
    __shared__ __align__(16) float lds[12608];   // 50.4 KB
    float* At = lds;                 // [4096]  A^T; aliased by Ag after phase 2
    float* Sf = lds + 4096;          // [64*65] self rows
    float* U  = lds + 8256;          // [64*68] query vectors
    int tid = threadIdx.x;
    int tilei = swz_tile(blockIdx.x);
    int fbase = tilei * 64;
    const float* feaT = ws + WS_FEAT;
    const float scale = 0.08838834764831845f;   // 1/sqrt(128)

    // phase 1: stage A^T and gathered self rows
    for (int i = tid; i < 4096; i += 256) At[i] = ws[WS_MT + i];
    {
        int r = tid >> 2;
        int face = fbase + r;
        int b = face / FP;
        int p = pool[face - b * FP];
        const float* src = feaT + ((long)(b * F_ALL + p)) * 64;
        int off = (tid & 3) * 4;
#pragma unroll
        for (int it = 0; it < 4; it++, off += 16) {
            float4 v = *(const float4*)(src + off);
            Sf[r * 65 + off + 0] = v.x;
            Sf[r * 65 + off + 1] = v.y;
            Sf[r * 65 + off + 2] = v.z;
            Sf[r * 65 + off + 3] = v.w;
        }
    }
    __syncthreads();

    // phase 2: U = Sf * A + v0
    int ti = tid & 15, tj = tid >> 4;
    {
        int f0 = ti * 4, o0 = tj * 4;
        float4 v0 = *(const float4*)&ws[WS_V0 + o0];
        float acc[4][4];
#pragma unroll
        for (int a = 0; a < 4; a++) {
            acc[a][0] = v0.x; acc[a][1] = v0.y; acc[a][2] = v0.z; acc[a][3] = v0.w;
        }
        for (int j = 0; j < 64; j++) {
            float4 wv = *(const float4*)&At[j * 64 + o0];
#pragma unroll
            for (int a = 0; a < 4; a++) {
                float av = Sf[(f0 + a) * 65 + j];
                acc[a][0] += av * wv.x;
                acc[a][1] += av * wv.y;
                acc[a][2] += av * wv.z;
                acc[a][3] += av * wv.w;
            }
        }
#pragma unroll
        for (int a = 0; a < 4; a++)
            *(float4*)&U[(f0 + a) * 68 + o0] =
                make_float4(acc[a][0], acc[a][1], acc[a][2], acc[a][3]);
    }
    __syncthreads();

    // phase 3: attention (wave = 4 faces, 4 iterations); results buffered in regs
    int lane = tid & 63;
    int il = lane & 15, c4 = il * 4;
    float4 a_res[4];
    for (int it = 0; it < 4; it++) {
        int fl = (tid >> 4) + it * 16;
        int face = fbase + fl;
        int b = face / FP;
        const float* fb = feaT + ((long)b * F_ALL) * 64 + c4;

        float4 sf = make_float4(Sf[fl * 65 + c4], Sf[fl * 65 + c4 + 1],
                                Sf[fl * 65 + c4 + 2], Sf[fl * 65 + c4 + 3]);
        float4 u = *(const float4*)&U[fl * 68 + c4];

        int rv = ring[face * KK + il];
        float4 nv[KK];
#pragma unroll
        for (int k = 0; k < KK; k++) {
            int rk = __shfl(rv, (lane & 48) | k, 64);
            nv[k] = *(const float4*)(fb + (long)rk * 64);
        }

        float l[KK + 1];
        l[0] = sum16(u.x * sf.x + u.y * sf.y + u.z * sf.z + u.w * sf.w) * scale;
#pragma unroll
        for (int k = 0; k < KK; k++)
            l[k + 1] = sum16(u.x * nv[k].x + u.y * nv[k].y + u.z * nv[k].z + u.w * nv[k].w) * scale;

        float m = l[0];
#pragma unroll
        for (int k = 1; k <= KK; k++) m = fmaxf(m, l[k]);
        float den = 0.f;
#pragma unroll
        for (int k = 0; k <= KK; k++) { l[k] = __expf(l[k] - m); den += l[k]; }
        float inv = 1.0f / den;

        float4 a;
        a.x = l[0] * sf.x; a.y = l[0] * sf.y; a.z = l[0] * sf.z; a.w = l[0] * sf.w;
#pragma unroll
        for (int k = 0; k < KK; k++) {
            a.x += l[k + 1] * nv[k].x;
            a.y += l[k + 1] * nv[k].y;
            a.z += l[k + 1] * nv[k].z;
            a.w += l[k + 1] * nv[k].w;
        }
        a.x *= inv; a.y *= inv; a.z *= inv; a.w *= inv;
        a_res[it] = a;
        *(float4*)&ws[WS_AGG + (long)face * 64 + c4] = a;
    }
    __syncthreads();            // Sf/U reads done -> safe to overwrite with Ag
    float* Ag = lds;            // [f*64+c]
#pragma unroll
    for (int it = 0; it < 4; it++) {
        int fl = (tid >> 4) + it * 16;
        *(float4*)&Ag[fl * 64 + c4] = a_res[it];
    }
    __syncthreads();

    // phase 4: per-block gram partial over the 64 faces in LDS
    float acc[4][4];
#pragma unroll
    for (int a = 0; a < 4; a++)
#pragma unroll
        for (int b = 0; b < 4; b++) acc[a][b] = 0.f;
    float gacc[4] = {0.f, 0.f, 0.f, 0.f};
#pragma unroll 4
    for (int f = 0; f < 64; f++) {
        float4 av = *(const float4*)&Ag[f * 64 + ti * 4];
        float4 bv = *(const float4*)&Ag[f * 64 + tj * 4];
        float avv[4] = {av.x, av.y, av.z, av.w};
        float bvv[4] = {bv.x, bv.y, bv.z, bv.w};
#pragma unroll
        for (int a = 0; a < 4; a++) {
#pragma unroll
            for (int b = 0; b < 4; b++) acc[a][b] += avv[a] * bvv[b];
            gacc[a] += avv[a];
        }
    }
    float* gp = ws + WS_GP;
#pragma unroll
    for (int a = 0; a < 4; a++)
        *(float4*)&gp[(long)tilei * 4096 + (ti * 4 + a) * 64 + tj * 4] =
            make_float4(acc[a][0], acc[a][1], acc[a][2], acc[a][3]);
    if (tj == 0)
        *(float4*)&ws[WS_SAP + tilei * 64 + ti * 4] =
            make_float4(gacc[0], gacc[1], gacc[2], gacc[3]);
}

// ---------- K3: reduce gram partials (256 blocks for G, 4 for sumA) ----------
__global__ __launch_bounds__(256) void k_gsum(float* __restrict__ ws) {
    __shared__ float red[256];
    int t = threadIdx.x;
    if (blockIdx.x < 256) {
        const float* gp = ws + WS_GP;
        int e16 = blockIdx.x * 16;          // 16-element column group
        int e = t & 15, c = t >> 4;         // 16 p-chunks
        int p0 = c * 40;
        int p1 = p0 + 40; if (p1 > NBLK) p1 = NBLK;
        float s0 = 0.f, s1 = 0.f, s2 = 0.f, s3 = 0.f;
        int p = p0;
        for (; p + 4 <= p1; p += 4) {
            s0 += gp[(long)(p + 0) * 4096 + e16 + e];
            s1 += gp[(long)(p + 1) * 4096 + e16 + e];
            s2 += gp[(long)(p + 2) * 4096 + e16 + e];
            s3 += gp[(long)(p + 3) * 4096 + e16 + e];
        }
        for (; p < p1; p++) s0 += gp[(long)p * 4096 + e16 + e];
        red[t] = (s0 + s1) + (s2 + s3);
        __syncthreads();
        if (t < 16) {
            float s = 0.f;
#pragma unroll
            for (int cc = 0; cc < 16; cc++) s += red[cc * 16 + t];
            ws[WS_G + e16 + t] = s;
        }
    } else {
        const float* sap = ws + WS_SAP;
        int bq = blockIdx.x - 256;          // 0..3
        int e = t & 63, c = t >> 6;
        int pidx = bq * 4 + c;              // global chunk 0..15
        int p0 = pidx * 40;
        int p1 = p0 + 40; if (p1 > NBLK) p1 = NBLK;
        float s0 = 0.f, s1 = 0.f, s2 = 0.f, s3 = 0.f;
        int p = p0;
        for (; p + 4 <= p1; p += 4) {
            s0 += sap[(p + 0) * 64 + e];
            s1 += sap[(p + 1) * 64 + e];
            s2 += sap[(p + 2) * 64 + e];
            s3 += sap[(p + 3) * 64 + e];
        }
        for (; p < p1; p++) s0 += sap[p * 64 + e];
        red[t] = (s0 + s1) + (s2 + s3);
        __syncthreads();
        if (t < 64) {
            float tot = red[t] + red[t + 64] + red[t + 128] + red[t + 192];
            atomicAdd(&ws[WS_SUMA + t], tot);   // 64 atomics x 4 blocks (zeroed in k_pre)
        }
    }
}

// ---------- K4: BN stats -> per-o scale/shift ----------
__global__ __launch_bounds__(256) void k_stats(const float* __restrict__ Wc,
                                               const float* __restrict__ bc,
                                               const float* __restrict__ gamma,
                                               const float* __restrict__ beta,
                                               float* __restrict__ ws) {
    __shared__ float Gs[4096];
    __shared__ float gs[64];
    __shared__ float qs[256];
    int tid = threadIdx.x;
    for (int i = tid; i < 4096; i += 256) Gs[i] = ws[WS_G + i];
    if (tid < 64) gs[tid] = ws[WS_SUMA + tid];
    __syncthreads();

    int o = tid & 127, h = tid >> 7;
    float w[64];
#pragma unroll
    for (int q = 0; q < 16; q++) {
        float4 t = *(const float4*)&Wc[o * 64 + q * 4];
        w[q * 4 + 0] = t.x; w[q * 4 + 1] = t.y; w[q * 4 + 2] = t.z; w[q * 4 + 3] = t.w;
    }
    float qp = 0.f;
    for (int i = h * 32; i < h * 32 + 32; i++) {
        float t = 0.f;
#pragma unroll
        for (int j = 0; j < 64; j++) t += Gs[i * 64 + j] * w[j];
        qp += Wc[o * 64 + i] * t;
    }
    qs[tid] = qp;
    __syncthreads();
    if (h == 0) {
        const float invN = 1.0f / (float)NFACE;
        float qform = qs[o] + qs[o + 128];
        float md = 0.f;
#pragma unroll
        for (int j = 0; j < 64; j++) md += gs[j] * w[j];
        float bco = bc[o];
        float mean = md * invN + bco;
        float ey2  = (qform + 2.f * bco * md) * invN + bco * bco;
        float var  = ey2 - mean * mean;
        float sc   = gamma[o] * rsqrtf(var + 1e-5f);
        ws[WS_SC + o] = sc;
        ws[WS_SH + o] = beta[o] + (bco - mean) * sc;
    }
}

// ---------- K5: out = relu((Wc*agg)*sc + sh)  [B,O,Fp] ----------
__global__ __launch_bounds__(256) void k_out(const float* __restrict__ Wc,
                                             const float* __restrict__ ws,
                                             float* __restrict__ out) {
    __shared__ __align__(16) float WcT[64 * 132];   // [j][o]
    __shared__ __align__(16) float AgT[64 * 68];    // [j][f]
    const float* agg = ws + WS_AGG;
    int tid = threadIdx.x;
    int fbase = blockIdx.x * 64;
    for (int i = tid; i < 128 * 64; i += 256) {
        int o = i >> 6, j = i & 63;
        WcT[j * 132 + o] = Wc[i];
    }
    for (int i = tid; i < 64 * 64; i += 256) {
        int f = i >> 6, j = i & 63;
        AgT[j * 68 + f] = agg[((long)(fbase + f)) * 64 + j];
    }
    __syncthreads();

    int tx = tid & 15, ty = tid >> 4;   // tx: 4 faces, ty: 8 outputs
    float acc[8][4];
#pragma unroll
    for (int a = 0; a < 8; a++)
#pragma unroll
        for (int b = 0; b < 4; b++) acc[a][b] = 0.f;

    for (int j = 0; j < 64; j++) {
        float4 w0 = *(const float4*)&WcT[j * 132 + ty * 8];
        float4 w1 = *(const float4*)&WcT[j * 132 + ty * 8 + 4];
        float4 a0 = *(const float4*)&AgT[j * 68 + tx * 4];
        float wv[8] = {w0.x, w0.y, w0.z, w0.w, w1.x, w1.y, w1.z, w1.w};
        float av[4] = {a0.x, a0.y, a0.z, a0.w};
#pragma unroll
        for (int oi = 0; oi < 8; oi++)
#pragma unroll
            for (int fi = 0; fi < 4; fi++) acc[oi][fi] += wv[oi] * av[fi];
    }

    int fg0 = fbase + tx * 4;
    int b   = fg0 / FP;
    int fp0 = fg0 - b * FP;             // 4-runs never cross batch boundary
#pragma unroll
    for (int oi = 0; oi < 8; oi++) {
        int o = ty * 8 + oi;
        float sc = ws[WS_SC + o];
        float sh = ws[WS_SH + o];
        float4 v;
        v.x = fmaxf(acc[oi][0] * sc + sh, 0.f);
        v.y = fmaxf(acc[oi][1] * sc + sh, 0.f);
        v.z = fmaxf(acc[oi][2] * sc + sh, 0.f);
        v.w = fmaxf(acc[oi][3] * sc + sh, 0.f);
        *(float4*)&out[((long)(b * OO + o)) * FP + fp0] = v;
    }
}

extern "C" void kernel_launch(void* const* d_in, const int* in_sizes, int n_in,
                              void* d_out, int out_size, void* d_ws, size_t ws_size,
                              hipStream_t stream) {
    const float* fea  = (const float*)d_in[0];
    const int*   ring = (const int*)d_in[1];
    const int*   pool = (const int*)d_in[2];
    const float* Wk = (const float*)d_in[4];
    const float* bk = (const float*)d_in[5];
    const float* Wq = (const float*)d_in[6];
    // bq unused: its logit contribution is constant per face -> cancels in softmax
    const float* Wc = (const float*)d_in[8];
    const float* bc = (const float*)d_in[9];
    const float* gamma = (const float*)d_in[10];
    const float* beta  = (const float*)d_in[11];

    float* out = (float*)d_out;
    float* ws  = (float*)d_ws;

    k_pre  <<<1268, 256, 0, stream>>>(fea, Wk, bk, Wq, ws);
    k_attn <<<NBLK, 256, 0, stream>>>(ring, pool, ws);
    k_gsum <<<260,  256, 0, stream>>>(ws);
    k_stats<<<1,    256, 0, stream>>>(Wc, bc, gamma, beta, ws);
    k_out  <<<NBLK, 256, 0, stream>>>(Wc, ws, out);
}

// Round 11
// 165.725 us; speedup vs baseline: 1.8151x; 1.0142x over previous
//
#include <hip/hip_runtime.h>

#define F_ALL 20000
#define FP    10000
#define BB    4
#define KK    16
#define OO    128
#define NFACE 40000
#define NBLK  625            // 64 faces per attn block

// workspace float offsets (~41 MB total)
#define WS_FEAT 0
#define WS_AGG  (BB*F_ALL*64)            // 5,120,000
#define WS_GP   (WS_AGG + NFACE*64)      // 7,680,000
#define WS_SAP  (WS_GP + NBLK*4096)      // 10,240,000
#define WS_MT   (WS_SAP + NBLK*64)       // 10,280,000  MT[j*64+i] = A[i][j]
#define WS_V0   (WS_MT + 4096)
#define WS_G    (WS_V0 + 64)
#define WS_SUMA (WS_G + 4096)
#define WS_SC   (WS_SUMA + 64)
#define WS_SH   (WS_SC + 128)

template<int CTRL>
__device__ __forceinline__ float dpp_add(float x) {
    return x + __int_as_float(__builtin_amdgcn_update_dpp(0, __float_as_int(x), CTRL, 0xF, 0xF, true));
}
// all-reduce sum within each 16-lane row (4 VALU DPP stages)
__device__ __forceinline__ float sum16(float x) {
    x = dpp_add<0x121>(x);
    x = dpp_add<0x122>(x);
    x = dpp_add<0x124>(x);
    x = dpp_add<0x128>(x);
    return x;
}

// XCD-locality swizzle: each XCD owns a CONTIGUOUS ~79-tile face range so its
// random-within-batch neighbor gathers stay in its private 4MB L2. (round-10: -6us)
__device__ __forceinline__ int swz_tile(int bid) {
    int q = bid & 7, s = bid >> 3;
    return (q == 0) ? s : (79 + (q - 1) * 78 + s);
}

// ---------- K1: transpose fea -> feaT (blocks 0..1251) + precompute (1252..1267) ----------
__global__ __launch_bounds__(256) void k_pre(const float* __restrict__ fea,
                                             const float* __restrict__ Wk,
                                             const float* __restrict__ bk,
                                             const float* __restrict__ Wq,
                                             float* __restrict__ ws) {
    __shared__ float tile[64][65];
    int tid = threadIdx.x;
    if (blockIdx.x < 1252) {
        int bb = blockIdx.x / 313;
        int tb = blockIdx.x % 313;
        int fbase = tb * 64;
        int x  = tid & 63;
        int y0 = tid >> 6;
        int f = fbase + x;
        float* feaT = ws + WS_FEAT;
        if (f < F_ALL) {
#pragma unroll
            for (int i = 0; i < 16; i++) {
                int c = y0 + i * 4;
                tile[c][x] = fea[((long)bb * 64 + c) * F_ALL + f];
            }
        }
        __syncthreads();
#pragma unroll
        for (int i = 0; i < 16; i++) {
            int fr = y0 + i * 4;
            int ff = fbase + fr;
            if (ff < F_ALL)
                feaT[((long)bb * F_ALL + ff) * 64 + x] = tile[x][fr];
        }
    } else {
        int idx = (blockIdx.x - 1252) * 256 + tid;    // 0..4095
        int j = idx >> 6, i = idx & 63;
        float acc = 0.f;
#pragma unroll 8
        for (int o = 0; o < 128; o++) acc += Wq[o * 64 + i] * Wk[o * 64 + j];
        ws[WS_MT + idx] = acc;                        // MT[j*64+i] = A[i][j]
        if (blockIdx.x == 1252 && tid < 64) {
            float a = 0.f;
            for (int o = 0; o < 128; o++) a += Wq[o * 64 + tid] * bk[o];
            ws[WS_V0 + tid] = a;
            ws[WS_SUMA + tid] = 0.f;                  // zero for k_gsum atomics
        }
    }
}

// ---------- K2: fused qvec(reg) + attention(online-sm) + gram partial ----------
// LDS 16.6KB (was 50.4): Sf only; Ag aliases it after phase 3. MT read from
// global (L1/L2-hot broadcast). u held in regs (static-indexed). nv chunked
// 2x8 with branchless online-softmax rescale -> VGPR ~100 -> ~16 waves/CU.
__global__ __launch_bounds__(256) void k_attn(const int* __restrict__ ring,
                                              const int* __restrict__ pool,
                                              float* __restrict__ ws) {
    __shared__ __align__(16) float lds[4160];    // Sf [64 rows, stride 65]; Ag aliases [0,4096)
    float* Sf = lds;
    int tid = threadIdx.x;
    int tilei = swz_tile(blockIdx.x);
    int fbase = tilei * 64;
    const float* feaT = ws + WS_FEAT;
    const float* MTg  = ws + WS_MT;
    const float scale = 0.08838834764831845f;   // 1/sqrt(128)

    // phase 1: gather self rows into Sf
    {
        int r = tid >> 2;
        int face = fbase + r;
        int b = face / FP;
        int p = pool[face - b * FP];
        const float* src = feaT + ((long)(b * F_ALL + p)) * 64;
        int off = (tid & 3) * 4;
#pragma unroll
        for (int it = 0; it < 4; it++, off += 16) {
            float4 v = *(const float4*)(src + off);
            Sf[r * 65 + off + 0] = v.x;
            Sf[r * 65 + off + 1] = v.y;
            Sf[r * 65 + off + 2] = v.z;
            Sf[r * 65 + off + 3] = v.w;
        }
    }
    __syncthreads();

    int lane = tid & 63;
    int il = lane & 15, c4 = il * 4;
    int f0 = tid >> 4;                  // face group 0..15; faces f0+16*it

    // phase 2: u[it] = A[c4..c4+3][:] . self[f0+16it] + v0   (u in registers)
    float4 u[4];
    {
        float4 v0 = *(const float4*)&ws[WS_V0 + c4];
        u[0] = v0; u[1] = v0; u[2] = v0; u[3] = v0;
#pragma unroll 8
        for (int j = 0; j < 64; j++) {
            float4 m4 = *(const float4*)&MTg[j * 64 + c4];   // L1/L2 broadcast
            float a0 = Sf[(f0     ) * 65 + j];
            float a1 = Sf[(f0 + 16) * 65 + j];
            float a2 = Sf[(f0 + 32) * 65 + j];
            float a3 = Sf[(f0 + 48) * 65 + j];
            u[0].x += m4.x * a0; u[0].y += m4.y * a0; u[0].z += m4.z * a0; u[0].w += m4.w * a0;
            u[1].x += m4.x * a1; u[1].y += m4.y * a1; u[1].z += m4.z * a1; u[1].w += m4.w * a1;
            u[2].x += m4.x * a2; u[2].y += m4.y * a2; u[2].z += m4.z * a2; u[2].w += m4.w * a2;
            u[3].x += m4.x * a3; u[3].y += m4.y * a3; u[3].z += m4.z * a3; u[3].w += m4.w * a3;
        }
    }

    // phase 3: attention with chunked (2x8) online softmax; results in regs
    float4 a_res[4];
#pragma unroll
    for (int it = 0; it < 4; it++) {
        int fl = f0 + it * 16;
        int face = fbase + fl;
        int b = face / FP;
        const float* fb = feaT + ((long)b * F_ALL) * 64 + c4;

        float4 sf = make_float4(Sf[fl * 65 + c4], Sf[fl * 65 + c4 + 1],
                                Sf[fl * 65 + c4 + 2], Sf[fl * 65 + c4 + 3]);
        float4 uu = u[it];
        int rv = ring[face * KK + il];              // lane il holds neighbor il

        float m = sum16(uu.x * sf.x + uu.y * sf.y + uu.z * sf.z + uu.w * sf.w) * scale;
        float den = 1.f;                            // exp(0) for self
        float4 acc = sf;
#pragma unroll
        for (int ch = 0; ch < 2; ch++) {
            float4 nv[8];
#pragma unroll
            for (int k = 0; k < 8; k++) {
                int rk = __shfl(rv, (lane & 48) | (ch * 8 + k), 64);
                nv[k] = *(const float4*)(fb + (long)rk * 64);
            }
            float l[8];
#pragma unroll
            for (int k = 0; k < 8; k++)
                l[k] = sum16(uu.x * nv[k].x + uu.y * nv[k].y +
                             uu.z * nv[k].z + uu.w * nv[k].w) * scale;
            float cm = l[0];
#pragma unroll
            for (int k = 1; k < 8; k++) cm = fmaxf(cm, l[k]);
            float nm = fmaxf(m, cm);
            float rs = __expf(m - nm);              // branchless rescale
            den *= rs;
            acc.x *= rs; acc.y *= rs; acc.z *= rs; acc.w *= rs;
            m = nm;
#pragma unroll
            for (int k = 0; k < 8; k++) {
                float e = __expf(l[k] - m);
                den += e;
                acc.x += e * nv[k].x;
                acc.y += e * nv[k].y;
                acc.z += e * nv[k].z;
                acc.w += e * nv[k].w;
            }
        }
        float inv = 1.0f / den;
        float4 a = make_float4(acc.x * inv, acc.y * inv, acc.z * inv, acc.w * inv);
        a_res[it] = a;
        *(float4*)&ws[WS_AGG + (long)face * 64 + c4] = a;
    }
    __syncthreads();            // all Sf reads done -> safe to overwrite with Ag
    float* Ag = lds;            // [f*64+c]
#pragma unroll
    for (int it = 0; it < 4; it++) {
        int fl = f0 + it * 16;
        *(float4*)&Ag[fl * 64 + c4] = a_res[it];
    }
    __syncthreads();

    // phase 4: per-block gram partial over the 64 faces in LDS
    int ti = tid & 15, tj = tid >> 4;
    float acc[4][4];
#pragma unroll
    for (int a = 0; a < 4; a++)
#pragma unroll
        for (int b = 0; b < 4; b++) acc[a][b] = 0.f;
    float gacc[4] = {0.f, 0.f, 0.f, 0.f};
#pragma unroll 4
    for (int f = 0; f < 64; f++) {
        float4 av = *(const float4*)&Ag[f * 64 + ti * 4];
        float4 bv = *(const float4*)&Ag[f * 64 + tj * 4];
        float avv[4] = {av.x, av.y, av.z, av.w};
        float bvv[4] = {bv.x, bv.y, bv.z, bv.w};
#pragma unroll
        for (int a = 0; a < 4; a++) {
#pragma unroll
            for (int b = 0; b < 4; b++) acc[a][b] += avv[a] * bvv[b];
            gacc[a] += avv[a];
        }
    }
    float* gp = ws + WS_GP;
#pragma unroll
    for (int a = 0; a < 4; a++)
        *(float4*)&gp[(long)tilei * 4096 + (ti * 4 + a) * 64 + tj * 4] =
            make_float4(acc[a][0], acc[a][1], acc[a][2], acc[a][3]);
    if (tj == 0)
        *(float4*)&ws[WS_SAP + tilei * 64 + ti * 4] =
            make_float4(gacc[0], gacc[1], gacc[2], gacc[3]);
}

// ---------- K3: reduce gram partials (256 blocks for G, 4 for sumA) ----------
__global__ __launch_bounds__(256) void k_gsum(float* __restrict__ ws) {
    __shared__ float red[256];
    int t = threadIdx.x;
    if (blockIdx.x < 256) {
        const float* gp = ws + WS_GP;
        int e16 = blockIdx.x * 16;          // 16-element column group
        int e = t & 15, c = t >> 4;         // 16 p-chunks
        int p0 = c * 40;
        int p1 = p0 + 40; if (p1 > NBLK) p1 = NBLK;
        float s0 = 0.f, s1 = 0.f, s2 = 0.f, s3 = 0.f;
        int p = p0;
        for (; p + 4 <= p1; p += 4) {
            s0 += gp[(long)(p + 0) * 4096 + e16 + e];
            s1 += gp[(long)(p + 1) * 4096 + e16 + e];
            s2 += gp[(long)(p + 2) * 4096 + e16 + e];
            s3 += gp[(long)(p + 3) * 4096 + e16 + e];
        }
        for (; p < p1; p++) s0 += gp[(long)p * 4096 + e16 + e];
        red[t] = (s0 + s1) + (s2 + s3);
        __syncthreads();
        if (t < 16) {
            float s = 0.f;
#pragma unroll
            for (int cc = 0; cc < 16; cc++) s += red[cc * 16 + t];
            ws[WS_G + e16 + t] = s;
        }
    } else {
        const float* sap = ws + WS_SAP;
        int bq = blockIdx.x - 256;          // 0..3
        int e = t & 63, c = t >> 6;
        int pidx = bq * 4 + c;              // global chunk 0..15
        int p0 = pidx * 40;
        int p1 = p0 + 40; if (p1 > NBLK) p1 = NBLK;
        float s0 = 0.f, s1 = 0.f, s2 = 0.f, s3 = 0.f;
        int p = p0;
        for (; p + 4 <= p1; p += 4) {
            s0 += sap[(p + 0) * 64 + e];
            s1 += sap[(p + 1) * 64 + e];
            s2 += sap[(p + 2) * 64 + e];
            s3 += sap[(p + 3) * 64 + e];
        }
        for (; p < p1; p++) s0 += sap[p * 64 + e];
        red[t] = (s0 + s1) + (s2 + s3);
        __syncthreads();
        if (t < 64) {
            float tot = red[t] + red[t + 64] + red[t + 128] + red[t + 192];
            atomicAdd(&ws[WS_SUMA + t], tot);   // 64 atomics x 4 blocks (zeroed in k_pre)
        }
    }
}

// ---------- K4: BN stats -> per-o scale/shift ----------
__global__ __launch_bounds__(256) void k_stats(const float* __restrict__ Wc,
                                               const float* __restrict__ bc,
                                               const float* __restrict__ gamma,
                                               const float* __restrict__ beta,
                                               float* __restrict__ ws) {
    __shared__ float Gs[4096];
    __shared__ float gs[64];
    __shared__ float qs[256];
    int tid = threadIdx.x;
    for (int i = tid; i < 4096; i += 256) Gs[i] = ws[WS_G + i];
    if (tid < 64) gs[tid] = ws[WS_SUMA + tid];
    __syncthreads();

    int o = tid & 127, h = tid >> 7;
    float w[64];
#pragma unroll
    for (int q = 0; q < 16; q++) {
        float4 t = *(const float4*)&Wc[o * 64 + q * 4];
        w[q * 4 + 0] = t.x; w[q * 4 + 1] = t.y; w[q * 4 + 2] = t.z; w[q * 4 + 3] = t.w;
    }
    float qp = 0.f;
    for (int i = h * 32; i < h * 32 + 32; i++) {
        float t = 0.f;
#pragma unroll
        for (int j = 0; j < 64; j++) t += Gs[i * 64 + j] * w[j];
        qp += Wc[o * 64 + i] * t;
    }
    qs[tid] = qp;
    __syncthreads();
    if (h == 0) {
        const float invN = 1.0f / (float)NFACE;
        float qform = qs[o] + qs[o + 128];
        float md = 0.f;
#pragma unroll
        for (int j = 0; j < 64; j++) md += gs[j] * w[j];
        float bco = bc[o];
        float mean = md * invN + bco;
        float ey2  = (qform + 2.f * bco * md) * invN + bco * bco;
        float var  = ey2 - mean * mean;
        float sc   = gamma[o] * rsqrtf(var + 1e-5f);
        ws[WS_SC + o] = sc;
        ws[WS_SH + o] = beta[o] + (bco - mean) * sc;
    }
}

// ---------- K5: out = relu((Wc*agg)*sc + sh)  [B,O,Fp] ----------
__global__ __launch_bounds__(256) void k_out(const float* __restrict__ Wc,
                                             const float* __restrict__ ws,
                                             float* __restrict__ out) {
    __shared__ __align__(16) float WcT[64 * 132];   // [j][o]
    __shared__ __align__(16) float AgT[64 * 68];    // [j][f]
    const float* agg = ws + WS_AGG;
    int tid = threadIdx.x;
    int fbase = blockIdx.x * 64;
    for (int i = tid; i < 128 * 64; i += 256) {
        int o = i >> 6, j = i & 63;
        WcT[j * 132 + o] = Wc[i];
    }
    for (int i = tid; i < 64 * 64; i += 256) {
        int f = i >> 6, j = i & 63;
        AgT[j * 68 + f] = agg[((long)(fbase + f)) * 64 + j];
    }
    __syncthreads();

    int tx = tid & 15, ty = tid >> 4;   // tx: 4 faces, ty: 8 outputs
    float acc[8][4];
#pragma unroll
    for (int a = 0; a < 8; a++)
#pragma unroll
        for (int b = 0; b < 4; b++) acc[a][b] = 0.f;

    for (int j = 0; j < 64; j++) {
        float4 w0 = *(const float4*)&WcT[j * 132 + ty * 8];
        float4 w1 = *(const float4*)&WcT[j * 132 + ty * 8 + 4];
        float4 a0 = *(const float4*)&AgT[j * 68 + tx * 4];
        float wv[8] = {w0.x, w0.y, w0.z, w0.w, w1.x, w1.y, w1.z, w1.w};
        float av[4] = {a0.x, a0.y, a0.z, a0.w};
#pragma unroll
        for (int oi = 0; oi < 8; oi++)
#pragma unroll
            for (int fi = 0; fi < 4; fi++) acc[oi][fi] += wv[oi] * av[fi];
    }

    int fg0 = fbase + tx * 4;
    int b   = fg0 / FP;
    int fp0 = fg0 - b * FP;             // 4-runs never cross batch boundary
#pragma unroll
    for (int oi = 0; oi < 8; oi++) {
        int o = ty * 8 + oi;
        float sc = ws[WS_SC + o];
        float sh = ws[WS_SH + o];
        float4 v;
        v.x = fmaxf(acc[oi][0] * sc + sh, 0.f);
        v.y = fmaxf(acc[oi][1] * sc + sh, 0.f);
        v.z = fmaxf(acc[oi][2] * sc + sh, 0.f);
        v.w = fmaxf(acc[oi][3] * sc + sh, 0.f);
        *(float4*)&out[((long)(b * OO + o)) * FP + fp0] = v;
    }
}

extern "C" void kernel_launch(void* const* d_in, const int* in_sizes, int n_in,
                              void* d_out, int out_size, void* d_ws, size_t ws_size,
                              hipStream_t stream) {
    const float* fea  = (const float*)d_in[0];
    const int*   ring = (const int*)d_in[1];
    const int*   pool = (const int*)d_in[2];
    const float* Wk = (const float*)d_in[4];
    const float* bk = (const float*)d_in[5];
    const float* Wq = (const float*)d_in[6];
    // bq unused: its logit contribution is constant per face -> cancels in softmax
    const float* Wc = (const float*)d_in[8];
    const float* bc = (const float*)d_in[9];
    const float* gamma = (const float*)d_in[10];
    const float* beta  = (const float*)d_in[11];

    float* out = (float*)d_out;
    float* ws  = (float*)d_ws;

    k_pre  <<<1268, 256, 0, stream>>>(fea, Wk, bk, Wq, ws);
    k_attn <<<NBLK, 256, 0, stream>>>(ring, pool, ws);
    k_gsum <<<260,  256, 0, stream>>>(ws);
    k_stats<<<1,    256, 0, stream>>>(Wc, bc, gamma, beta, ws);
    k_out  <<<NBLK, 256, 0, stream>>>(Wc, ws, out);
}

// Round 12
// 165.244 us; speedup vs baseline: 1.8204x; 1.0029x over previous
//
#include <hip/hip_runtime.h>

#define F_ALL 20000
#define FP    10000
#define BB    4
#define KK    16
#define OO    128
#define NFACE 40000
#define NBLK  625            // 64 faces per attn block

// workspace float offsets (~41 MB total)
// WS_FEAT now holds bf16 [B,F,64] (uses half the region; offsets kept stable)
#define WS_FEAT 0
#define WS_AGG  (BB*F_ALL*64)            // 5,120,000
#define WS_GP   (WS_AGG + NFACE*64)      // 7,680,000
#define WS_SAP  (WS_GP + NBLK*4096)      // 10,240,000
#define WS_MT   (WS_SAP + NBLK*64)       // 10,280,000  MT[j*64+i] = A[i][j]
#define WS_V0   (WS_MT + 4096)
#define WS_G    (WS_V0 + 64)
#define WS_SUMA (WS_G + 4096)
#define WS_SC   (WS_SUMA + 64)
#define WS_SH   (WS_SC + 128)

template<int CTRL>
__device__ __forceinline__ float dpp_add(float x) {
    return x + __int_as_float(__builtin_amdgcn_update_dpp(0, __float_as_int(x), CTRL, 0xF, 0xF, true));
}
// all-reduce sum within each 16-lane row (4 VALU DPP stages)
__device__ __forceinline__ float sum16(float x) {
    x = dpp_add<0x121>(x);
    x = dpp_add<0x122>(x);
    x = dpp_add<0x124>(x);
    x = dpp_add<0x128>(x);
    return x;
}

// XCD-locality swizzle: each XCD owns a CONTIGUOUS ~79-tile face range so its
// random-within-batch neighbor gathers stay in its private 4MB L2. (round-10: -6us)
__device__ __forceinline__ int swz_tile(int bid) {
    int q = bid & 7, s = bid >> 3;
    return (q == 0) ? s : (79 + (q - 1) * 78 + s);
}

// fp32 -> bf16 (round-to-nearest-even), and unpack helpers
__device__ __forceinline__ unsigned int f2bf(float f) {
    unsigned int u = __float_as_uint(f);
    return (u + 0x7FFFu + ((u >> 16) & 1u)) >> 16;
}
__device__ __forceinline__ float b2f(unsigned short h) {
    return __uint_as_float(((unsigned int)h) << 16);
}
__device__ __forceinline__ void up2(unsigned int v, float* d) {
    d[0] = __uint_as_float((v & 0xFFFFu) << 16);
    d[1] = __uint_as_float(v & 0xFFFF0000u);
}

// ---------- K1: transpose fea -> feaT(bf16) (blocks 0..1251) + precompute ----------
__global__ __launch_bounds__(256) void k_pre(const float* __restrict__ fea,
                                             const float* __restrict__ Wk,
                                             const float* __restrict__ bk,
                                             const float* __restrict__ Wq,
                                             float* __restrict__ ws) {
    __shared__ float tile[64][65];
    int tid = threadIdx.x;
    if (blockIdx.x < 1252) {
        int bb = blockIdx.x / 313;
        int tb = blockIdx.x % 313;
        int fbase = tb * 64;
        int x  = tid & 63;
        int y0 = tid >> 6;
        int f = fbase + x;
        if (f < F_ALL) {
#pragma unroll
            for (int i = 0; i < 16; i++) {
                int c = y0 + i * 4;
                tile[c][x] = fea[((long)bb * 64 + c) * F_ALL + f];
            }
        }
        __syncthreads();
        // write bf16 rows [face][64ch], packed as uint pairs
        unsigned int* feaTh = (unsigned int*)(ws + WS_FEAT);   // 32 uints per row
        int xc = (tid & 31) * 2;     // channel pair
        int yr = tid >> 5;           // 0..7
#pragma unroll
        for (int i = 0; i < 8; i++) {
            int fr = yr + i * 8;
            int ff = fbase + fr;
            if (ff < F_ALL) {
                unsigned int lo = f2bf(tile[xc][fr]);
                unsigned int hi = f2bf(tile[xc + 1][fr]);
                feaTh[(long)(bb * F_ALL + ff) * 32 + (tid & 31)] = lo | (hi << 16);
            }
        }
    } else {
        int idx = (blockIdx.x - 1252) * 256 + tid;    // 0..4095
        int j = idx >> 6, i = idx & 63;
        float acc = 0.f;
#pragma unroll 8
        for (int o = 0; o < 128; o++) acc += Wq[o * 64 + i] * Wk[o * 64 + j];
        ws[WS_MT + idx] = acc;                        // MT[j*64+i] = A[i][j]
        if (blockIdx.x == 1252 && tid < 64) {
            float a = 0.f;
            for (int o = 0; o < 128; o++) a += Wq[o * 64 + tid] * bk[o];
            ws[WS_V0 + tid] = a;
            ws[WS_SUMA + tid] = 0.f;                  // zero for k_gsum atomics
        }
    }
}

// ---------- K2: fused qvec(reg) + attention(online-sm, bf16 gathers) + gram ----------
__global__ __launch_bounds__(256) void k_attn(const int* __restrict__ ring,
                                              const int* __restrict__ pool,
                                              float* __restrict__ ws) {
    __shared__ __align__(16) float lds[4160];    // Sf [64 rows, stride 65]; Ag aliases [0,4096)
    float* Sf = lds;
    int tid = threadIdx.x;
    int tilei = swz_tile(blockIdx.x);
    int fbase = tilei * 64;
    const unsigned short* feaTh = (const unsigned short*)(ws + WS_FEAT);
    const float* MTg  = ws + WS_MT;
    const float scale = 0.08838834764831845f;   // 1/sqrt(128)

    // phase 1: gather self rows (bf16, 128B each) into Sf (f32)
    {
        int r = tid >> 2;
        int face = fbase + r;
        int b = face / FP;
        int p = pool[face - b * FP];
        const uint4* src = (const uint4*)(feaTh + ((long)(b * F_ALL + p)) * 64);
        int q = tid & 3;
        uint4 A  = src[q * 2];
        uint4 Bv = src[q * 2 + 1];
        float* d = &Sf[r * 65 + q * 16];
        up2(A.x,  d +  0); up2(A.y,  d +  2); up2(A.z,  d +  4); up2(A.w,  d +  6);
        up2(Bv.x, d +  8); up2(Bv.y, d + 10); up2(Bv.z, d + 12); up2(Bv.w, d + 14);
    }
    __syncthreads();

    int lane = tid & 63;
    int il = lane & 15, c4 = il * 4;
    int f0 = tid >> 4;                  // face group 0..15; faces f0+16*it

    // phase 2: u[it] = A[c4..c4+3][:] . self[f0+16it] + v0   (u in registers)
    float4 u[4];
    {
        float4 v0 = *(const float4*)&ws[WS_V0 + c4];
        u[0] = v0; u[1] = v0; u[2] = v0; u[3] = v0;
#pragma unroll 8
        for (int j = 0; j < 64; j++) {
            float4 m4 = *(const float4*)&MTg[j * 64 + c4];   // L1/L2 broadcast
            float a0 = Sf[(f0     ) * 65 + j];
            float a1 = Sf[(f0 + 16) * 65 + j];
            float a2 = Sf[(f0 + 32) * 65 + j];
            float a3 = Sf[(f0 + 48) * 65 + j];
            u[0].x += m4.x * a0; u[0].y += m4.y * a0; u[0].z += m4.z * a0; u[0].w += m4.w * a0;
            u[1].x += m4.x * a1; u[1].y += m4.y * a1; u[1].z += m4.z * a1; u[1].w += m4.w * a1;
            u[2].x += m4.x * a2; u[2].y += m4.y * a2; u[2].z += m4.z * a2; u[2].w += m4.w * a2;
            u[3].x += m4.x * a3; u[3].y += m4.y * a3; u[3].z += m4.z * a3; u[3].w += m4.w * a3;
        }
    }

    // phase 3: attention with chunked (2x8) online softmax; bf16 neighbor rows
    float4 a_res[4];
#pragma unroll
    for (int it = 0; it < 4; it++) {
        int fl = f0 + it * 16;
        int face = fbase + fl;
        int b = face / FP;
        const unsigned short* fb = feaTh + (long)b * F_ALL * 64 + c4;

        float4 sf = make_float4(Sf[fl * 65 + c4], Sf[fl * 65 + c4 + 1],
                                Sf[fl * 65 + c4 + 2], Sf[fl * 65 + c4 + 3]);
        float4 uu = u[it];
        int rv = ring[face * KK + il];              // lane il holds neighbor il

        float m = sum16(uu.x * sf.x + uu.y * sf.y + uu.z * sf.z + uu.w * sf.w) * scale;
        float den = 1.f;                            // exp(0) for self
        float4 acc = sf;
#pragma unroll
        for (int ch = 0; ch < 2; ch++) {
            float4 nv[8];
#pragma unroll
            for (int k = 0; k < 8; k++) {
                int rk = __shfl(rv, (lane & 48) | (ch * 8 + k), 64);
                ushort4 hv = *(const ushort4*)(fb + (long)rk * 64);
                nv[k] = make_float4(b2f(hv.x), b2f(hv.y), b2f(hv.z), b2f(hv.w));
            }
            float l[8];
#pragma unroll
            for (int k = 0; k < 8; k++)
                l[k] = sum16(uu.x * nv[k].x + uu.y * nv[k].y +
                             uu.z * nv[k].z + uu.w * nv[k].w) * scale;
            float cm = l[0];
#pragma unroll
            for (int k = 1; k < 8; k++) cm = fmaxf(cm, l[k]);
            float nm = fmaxf(m, cm);
            float rs = __expf(m - nm);              // branchless rescale
            den *= rs;
            acc.x *= rs; acc.y *= rs; acc.z *= rs; acc.w *= rs;
            m = nm;
#pragma unroll
            for (int k = 0; k < 8; k++) {
                float e = __expf(l[k] - m);
                den += e;
                acc.x += e * nv[k].x;
                acc.y += e * nv[k].y;
                acc.z += e * nv[k].z;
                acc.w += e * nv[k].w;
            }
        }
        float inv = 1.0f / den;
        float4 a = make_float4(acc.x * inv, acc.y * inv, acc.z * inv, acc.w * inv);
        a_res[it] = a;
        *(float4*)&ws[WS_AGG + (long)face * 64 + c4] = a;
    }
    __syncthreads();            // all Sf reads done -> safe to overwrite with Ag
    float* Ag = lds;            // [f*64+c]
#pragma unroll
    for (int it = 0; it < 4; it++) {
        int fl = f0 + it * 16;
        *(float4*)&Ag[fl * 64 + c4] = a_res[it];
    }
    __syncthreads();

    // phase 4: per-block gram partial over the 64 faces in LDS
    int ti = tid & 15, tj = tid >> 4;
    float acc[4][4];
#pragma unroll
    for (int a = 0; a < 4; a++)
#pragma unroll
        for (int b = 0; b < 4; b++) acc[a][b] = 0.f;
    float gacc[4] = {0.f, 0.f, 0.f, 0.f};
#pragma unroll 4
    for (int f = 0; f < 64; f++) {
        float4 av = *(const float4*)&Ag[f * 64 + ti * 4];
        float4 bv = *(const float4*)&Ag[f * 64 + tj * 4];
        float avv[4] = {av.x, av.y, av.z, av.w};
        float bvv[4] = {bv.x, bv.y, bv.z, bv.w};
#pragma unroll
        for (int a = 0; a < 4; a++) {
#pragma unroll
            for (int b = 0; b < 4; b++) acc[a][b] += avv[a] * bvv[b];
            gacc[a] += avv[a];
        }
    }
    float* gp = ws + WS_GP;
#pragma unroll
    for (int a = 0; a < 4; a++)
        *(float4*)&gp[(long)tilei * 4096 + (ti * 4 + a) * 64 + tj * 4] =
            make_float4(acc[a][0], acc[a][1], acc[a][2], acc[a][3]);
    if (tj == 0)
        *(float4*)&ws[WS_SAP + tilei * 64 + ti * 4] =
            make_float4(gacc[0], gacc[1], gacc[2], gacc[3]);
}

// ---------- K3: reduce gram partials (256 blocks for G, 4 for sumA) ----------
__global__ __launch_bounds__(256) void k_gsum(float* __restrict__ ws) {
    __shared__ float red[256];
    int t = threadIdx.x;
    if (blockIdx.x < 256) {
        const float* gp = ws + WS_GP;
        int e16 = blockIdx.x * 16;          // 16-element column group
        int e = t & 15, c = t >> 4;         // 16 p-chunks
        int p0 = c * 40;
        int p1 = p0 + 40; if (p1 > NBLK) p1 = NBLK;
        float s0 = 0.f, s1 = 0.f, s2 = 0.f, s3 = 0.f;
        int p = p0;
        for (; p + 4 <= p1; p += 4) {
            s0 += gp[(long)(p + 0) * 4096 + e16 + e];
            s1 += gp[(long)(p + 1) * 4096 + e16 + e];
            s2 += gp[(long)(p + 2) * 4096 + e16 + e];
            s3 += gp[(long)(p + 3) * 4096 + e16 + e];
        }
        for (; p < p1; p++) s0 += gp[(long)p * 4096 + e16 + e];
        red[t] = (s0 + s1) + (s2 + s3);
        __syncthreads();
        if (t < 16) {
            float s = 0.f;
#pragma unroll
            for (int cc = 0; cc < 16; cc++) s += red[cc * 16 + t];
            ws[WS_G + e16 + t] = s;
        }
    } else {
        const float* sap = ws + WS_SAP;
        int bq = blockIdx.x - 256;          // 0..3
        int e = t & 63, c = t >> 6;
        int pidx = bq * 4 + c;              // global chunk 0..15
        int p0 = pidx * 40;
        int p1 = p0 + 40; if (p1 > NBLK) p1 = NBLK;
        float s0 = 0.f, s1 = 0.f, s2 = 0.f, s3 = 0.f;
        int p = p0;
        for (; p + 4 <= p1; p += 4) {
            s0 += sap[(p + 0) * 64 + e];
            s1 += sap[(p + 1) * 64 + e];
            s2 += sap[(p + 2) * 64 + e];
            s3 += sap[(p + 3) * 64 + e];
        }
        for (; p < p1; p++) s0 += sap[p * 64 + e];
        red[t] = (s0 + s1) + (s2 + s3);
        __syncthreads();
        if (t < 64) {
            float tot = red[t] + red[t + 64] + red[t + 128] + red[t + 192];
            atomicAdd(&ws[WS_SUMA + t], tot);   // 64 atomics x 4 blocks (zeroed in k_pre)
        }
    }
}

// ---------- K4: BN stats -> per-o scale/shift ----------
__global__ __launch_bounds__(256) void k_stats(const float* __restrict__ Wc,
                                               const float* __restrict__ bc,
                                               const float* __restrict__ gamma,
                                               const float* __restrict__ beta,
                                               float* __restrict__ ws) {
    __shared__ float Gs[4096];
    __shared__ float gs[64];
    __shared__ float qs[256];
    int tid = threadIdx.x;
    for (int i = tid; i < 4096; i += 256) Gs[i] = ws[WS_G + i];
    if (tid < 64) gs[tid] = ws[WS_SUMA + tid];
    __syncthreads();

    int o = tid & 127, h = tid >> 7;
    float w[64];
#pragma unroll
    for (int q = 0; q < 16; q++) {
        float4 t = *(const float4*)&Wc[o * 64 + q * 4];
        w[q * 4 + 0] = t.x; w[q * 4 + 1] = t.y; w[q * 4 + 2] = t.z; w[q * 4 + 3] = t.w;
    }
    float qp = 0.f;
    for (int i = h * 32; i < h * 32 + 32; i++) {
        float t = 0.f;
#pragma unroll
        for (int j = 0; j < 64; j++) t += Gs[i * 64 + j] * w[j];
        qp += Wc[o * 64 + i] * t;
    }
    qs[tid] = qp;
    __syncthreads();
    if (h == 0) {
        const float invN = 1.0f / (float)NFACE;
        float qform = qs[o] + qs[o + 128];
        float md = 0.f;
#pragma unroll
        for (int j = 0; j < 64; j++) md += gs[j] * w[j];
        float bco = bc[o];
        float mean = md * invN + bco;
        float ey2  = (qform + 2.f * bco * md) * invN + bco * bco;
        float var  = ey2 - mean * mean;
        float sc   = gamma[o] * rsqrtf(var + 1e-5f);
        ws[WS_SC + o] = sc;
        ws[WS_SH + o] = beta[o] + (bco - mean) * sc;
    }
}

// ---------- K5: out = relu((Wc*agg)*sc + sh)  [B,O,Fp] ----------
__global__ __launch_bounds__(256) void k_out(const float* __restrict__ Wc,
                                             const float* __restrict__ ws,
                                             float* __restrict__ out) {
    __shared__ __align__(16) float WcT[64 * 132];   // [j][o]
    __shared__ __align__(16) float AgT[64 * 68];    // [j][f]
    const float* agg = ws + WS_AGG;
    int tid = threadIdx.x;
    int fbase = blockIdx.x * 64;
    for (int i = tid; i < 128 * 64; i += 256) {
        int o = i >> 6, j = i & 63;
        WcT[j * 132 + o] = Wc[i];
    }
    for (int i = tid; i < 64 * 64; i += 256) {
        int f = i >> 6, j = i & 63;
        AgT[j * 68 + f] = agg[((long)(fbase + f)) * 64 + j];
    }
    __syncthreads();

    int tx = tid & 15, ty = tid >> 4;   // tx: 4 faces, ty: 8 outputs
    float acc[8][4];
#pragma unroll
    for (int a = 0; a < 8; a++)
#pragma unroll
        for (int b = 0; b < 4; b++) acc[a][b] = 0.f;

    for (int j = 0; j < 64; j++) {
        float4 w0 = *(const float4*)&WcT[j * 132 + ty * 8];
        float4 w1 = *(const float4*)&WcT[j * 132 + ty * 8 + 4];
        float4 a0 = *(const float4*)&AgT[j * 68 + tx * 4];
        float wv[8] = {w0.x, w0.y, w0.z, w0.w, w1.x, w1.y, w1.z, w1.w};
        float av[4] = {a0.x, a0.y, a0.z, a0.w};
#pragma unroll
        for (int oi = 0; oi < 8; oi++)
#pragma unroll
            for (int fi = 0; fi < 4; fi++) acc[oi][fi] += wv[oi] * av[fi];
    }

    int fg0 = fbase + tx * 4;
    int b   = fg0 / FP;
    int fp0 = fg0 - b * FP;             // 4-runs never cross batch boundary
#pragma unroll
    for (int oi = 0; oi < 8; oi++) {
        int o = ty * 8 + oi;
        float sc = ws[WS_SC + o];
        float sh = ws[WS_SH + o];
        float4 v;
        v.x = fmaxf(acc[oi][0] * sc + sh, 0.f);
        v.y = fmaxf(acc[oi][1] * sc + sh, 0.f);
        v.z = fmaxf(acc[oi][2] * sc + sh, 0.f);
        v.w = fmaxf(acc[oi][3] * sc + sh, 0.f);
        *(float4*)&out[((long)(b * OO + o)) * FP + fp0] = v;
    }
}

extern "C" void kernel_launch(void* const* d_in, const int* in_sizes, int n_in,
                              void* d_out, int out_size, void* d_ws, size_t ws_size,
                              hipStream_t stream) {
    const float* fea  = (const float*)d_in[0];
    const int*   ring = (const int*)d_in[1];
    const int*   pool = (const int*)d_in[2];
    const float* Wk = (const float*)d_in[4];
    const float* bk = (const float*)d_in[5];
    const float* Wq = (const float*)d_in[6];
    // bq unused: its logit contribution is constant per face -> cancels in softmax
    const float* Wc = (const float*)d_in[8];
    const float* bc = (const float*)d_in[9];
    const float* gamma = (const float*)d_in[10];
    const float* beta  = (const float*)d_in[11];

    float* out = (float*)d_out;
    float* ws  = (float*)d_ws;

    k_pre  <<<1268, 256, 0, stream>>>(fea, Wk, bk, Wq, ws);
    k_attn <<<NBLK, 256, 0, stream>>>(ring, pool, ws);
    k_gsum <<<260,  256, 0, stream>>>(ws);
    k_stats<<<1,    256, 0, stream>>>(Wc, bc, gamma, beta, ws);
    k_out  <<<NBLK, 256, 0, stream>>>(Wc, ws, out);
}